// Round 4
// baseline (283.174 us; speedup 1.0000x reference)
//
#include <hip/hip_runtime.h>
#include <hip/hip_bf16.h>

#define D_MODEL 1024
#define N_SEQ   2048
#define N_B     2
#define M_ROWS  (N_B * N_SEQ)   // 4096

typedef __attribute__((ext_vector_type(8))) short bf16x8;
typedef __attribute__((ext_vector_type(4))) float f32x4;

typedef const __attribute__((address_space(1))) unsigned int gu32_t;
typedef __attribute__((address_space(3))) unsigned int lu32_t;

__device__ __forceinline__ void gload16(const void* g, void* l) {
  // async global->LDS, 16B per lane; LDS dest = wave-uniform base + lane*16
  __builtin_amdgcn_global_load_lds((gu32_t*)g, (lu32_t*)l, 16, 0, 0);
}

__device__ inline unsigned short f2bf(float f) {
  union { float f; unsigned int u; } v; v.f = f;
  unsigned int r = (v.u + 0x7FFFu + ((v.u >> 16) & 1u)) >> 16;
  return (unsigned short)r;
}

constexpr size_t XEL = (size_t)M_ROWS * D_MODEL;     // 4194304
constexpr size_t WEL = (size_t)D_MODEL * D_MODEL;    // 1048576

// ---------------------------------------------------------------------------
// fp32 -> bf16 convert for [x (4M) | Wq | Wk | Wv | Wo (1M each)] -> ws
// ---------------------------------------------------------------------------
__launch_bounds__(256)
__global__ void cvt_kernel(const float* __restrict__ x,
                           const float* __restrict__ wq, const float* __restrict__ wk,
                           const float* __restrict__ wv, const float* __restrict__ wo,
                           unsigned short* __restrict__ dst) {
  size_t i = ((size_t)blockIdx.x * 256 + threadIdx.x) * 8;
  if (i >= XEL + 4 * WEL) return;
  const float* s; size_t off = i;
  if (off < XEL)                { s = x; }
  else if (off < XEL + WEL)     { s = wq; off -= XEL; }
  else if (off < XEL + 2*WEL)   { s = wk; off -= XEL + WEL; }
  else if (off < XEL + 3*WEL)   { s = wv; off -= XEL + 2*WEL; }
  else                          { s = wo; off -= XEL + 3*WEL; }
  float4 f0 = *(const float4*)(s + off);
  float4 f1 = *(const float4*)(s + off + 4);
  unsigned short t[8] = { f2bf(f0.x), f2bf(f0.y), f2bf(f0.z), f2bf(f0.w),
                          f2bf(f1.x), f2bf(f1.y), f2bf(f1.z), f2bf(f1.w) };
  *(uint4*)(dst + i) = *(const uint4*)t;
}

// ---------------------------------------------------------------------------
// m97-style 128x128 bf16 mainloop: C = A(128 x 1024) * Bw(128 rows x 1024)^T
// 4 waves in 2x2; wave (wr,wc) owns rows wr*64.., cols wc*64..; acc[mi][ci].
// ---------------------------------------------------------------------------
__device__ __forceinline__ void mainloop128(const unsigned short* __restrict__ A,
                                            const unsigned short* __restrict__ Bw,
                                            int m0, int e0,
                                            unsigned short* As, unsigned short* Bs,
                                            f32x4 (&acc)[4][4]) {
  const int tid  = threadIdx.x;
  const int wave = tid >> 6, lane = tid & 63;
  const int l16 = lane & 15, quad = lane >> 4;
  const int wr = wave >> 1, wc = wave & 1;

  for (int kt = 0; kt < D_MODEL / 64; ++kt) {
    const int k0 = kt * 64;
#pragma unroll
    for (int r = 0; r < 4; ++r) {
      int c = r * 256 + tid;                 // chunk of 8 ushorts
      int row = c >> 3, col8 = c & 7;
      gload16(A + (size_t)(m0 + row) * D_MODEL + k0 + col8 * 8,
              As + (size_t)(r * 256 + wave * 64) * 8);
    }
#pragma unroll
    for (int r = 0; r < 4; ++r) {
      int c = r * 256 + tid;
      int row = c >> 3, col8 = c & 7;
      gload16(Bw + (size_t)(e0 + row) * D_MODEL + k0 + col8 * 8,
              Bs + (size_t)(r * 256 + wave * 64) * 8);
    }
    __syncthreads();
#pragma unroll
    for (int ks = 0; ks < 2; ++ks) {
      bf16x8 af[4], bfr[4];
#pragma unroll
      for (int mi = 0; mi < 4; ++mi)
        af[mi] = *(const bf16x8*)(As + (size_t)(wr * 64 + mi * 16 + l16) * 64 + ks * 32 + quad * 8);
#pragma unroll
      for (int ci = 0; ci < 4; ++ci)
        bfr[ci] = *(const bf16x8*)(Bs + (size_t)(wc * 64 + ci * 16 + l16) * 64 + ks * 32 + quad * 8);
#pragma unroll
      for (int mi = 0; mi < 4; ++mi)
#pragma unroll
        for (int ci = 0; ci < 4; ++ci)
          acc[mi][ci] = __builtin_amdgcn_mfma_f32_16x16x32_bf16(af[mi], bfr[ci], acc[mi][ci], 0, 0, 0);
    }
    __syncthreads();
  }
}

// ---------------------------------------------------------------------------
// Fused Q/K/V projection. grid (32, 24): by -> {mat = by>>3, e0 = (by&7)*128}.
// mat 0 (q): LN epilogue with 0.125 softmax scale folded in.
// mat 1 (k): LN epilogue.
// mat 2 (v): V stored TRANSPOSED per (b,h) via LDS repack, coalesced rows.
// ---------------------------------------------------------------------------
__launch_bounds__(256)
__global__ void qkv_gemm(const unsigned short* __restrict__ xb,
                         const unsigned short* __restrict__ wb,   // wq|wk|wv bf16
                         const float* __restrict__ bq, const float* __restrict__ bk,
                         const float* __restrict__ bv,
                         const float* __restrict__ qg, const float* __restrict__ qbeta,
                         const float* __restrict__ kg, const float* __restrict__ kbeta,
                         unsigned short* __restrict__ qkout,      // qn | kn
                         unsigned short* __restrict__ vt) {
  __shared__ unsigned short As[128 * 64];
  __shared__ unsigned short Bs[128 * 64];
  const int m0  = blockIdx.x * 128;
  const int by  = blockIdx.y;
  const int mat = by >> 3;
  const int e0  = (by & 7) * 128;
  const unsigned short* Bw = wb + (size_t)mat * WEL;

  f32x4 acc[4][4];
#pragma unroll
  for (int mi = 0; mi < 4; ++mi)
#pragma unroll
    for (int ci = 0; ci < 4; ++ci) acc[mi][ci] = f32x4{0.f, 0.f, 0.f, 0.f};

  mainloop128(xb, Bw, m0, e0, As, Bs, acc);

  const int lane = threadIdx.x & 63, wave = threadIdx.x >> 6;
  const int l16 = lane & 15, quad = lane >> 4;
  const int wr = wave >> 1, wc = wave & 1;
  const int colbase = e0 + wc * 64;          // multiple of 64 -> one head per wave

  const float* bias = (mat == 0) ? bq : ((mat == 1) ? bk : bv);
  float bcol[4];
#pragma unroll
  for (int ci = 0; ci < 4; ++ci) bcol[ci] = bias[colbase + ci * 16 + l16];
#pragma unroll
  for (int mi = 0; mi < 4; ++mi)
#pragma unroll
    for (int ci = 0; ci < 4; ++ci)
#pragma unroll
      for (int r = 0; r < 4; ++r) acc[mi][ci][r] += bcol[ci];

  if (mat < 2) {
    const float* gamma = (mat == 0) ? qg : kg;
    const float* beta  = (mat == 0) ? qbeta : kbeta;
    const float sc = (mat == 0) ? 0.125f : 1.0f;   // fold softmax scale into q
    float g4[4], bt4[4];
#pragma unroll
    for (int ci = 0; ci < 4; ++ci) {
      g4[ci] = gamma[ci * 16 + l16] * sc;
      bt4[ci] = beta[ci * 16 + l16] * sc;
    }
#pragma unroll
    for (int mi = 0; mi < 4; ++mi)
#pragma unroll
      for (int r = 0; r < 4; ++r) {
        float s = acc[mi][0][r] + acc[mi][1][r] + acc[mi][2][r] + acc[mi][3][r];
        s += __shfl_xor(s, 1); s += __shfl_xor(s, 2);
        s += __shfl_xor(s, 4); s += __shfl_xor(s, 8);
        float mean = s * (1.f / 64.f);
        float d0 = acc[mi][0][r] - mean, d1 = acc[mi][1][r] - mean;
        float d2 = acc[mi][2][r] - mean, d3 = acc[mi][3][r] - mean;
        float q = d0 * d0 + d1 * d1 + d2 * d2 + d3 * d3;
        q += __shfl_xor(q, 1); q += __shfl_xor(q, 2);
        q += __shfl_xor(q, 4); q += __shfl_xor(q, 8);
        float rs = rsqrtf(q * (1.f / 64.f) + 1e-6f);
        acc[mi][0][r] = d0 * rs * g4[0] + bt4[0];
        acc[mi][1][r] = d1 * rs * g4[1] + bt4[1];
        acc[mi][2][r] = d2 * rs * g4[2] + bt4[2];
        acc[mi][3][r] = d3 * rs * g4[3] + bt4[3];
      }
    unsigned short* out = qkout + (size_t)mat * XEL;
#pragma unroll
    for (int mi = 0; mi < 4; ++mi)
#pragma unroll
      for (int ci = 0; ci < 4; ++ci) {
        int col = colbase + ci * 16 + l16;
#pragma unroll
        for (int r = 0; r < 4; ++r) {
          int row = m0 + wr * 64 + mi * 16 + quad * 4 + r;
          out[(size_t)row * D_MODEL + col] = f2bf(acc[mi][ci][r]);
        }
      }
  } else {
    // V transpose via wave-private LDS scratch (col-swizzled), then each lane
    // stores one full d-row (128B) as 8x dwordx4 -> coalesced.
    // scratch layout: scr[d_local*64 + (n_local ^ ((d_local&3)*16))]
    unsigned short* scr = ((wave < 2) ? As : Bs) + (size_t)(wave & 1) * 4096;
#pragma unroll
    for (int ci = 0; ci < 4; ++ci) {
      int dl = ci * 16 + l16;
      int sw = (dl & 3) * 16;
#pragma unroll
      for (int mi = 0; mi < 4; ++mi)
#pragma unroll
        for (int r = 0; r < 4; ++r) {
          int nl = mi * 16 + quad * 4 + r;
          scr[dl * 64 + (nl ^ sw)] = f2bf(acc[mi][ci][r]);
        }
    }
    __builtin_amdgcn_wave_barrier();
    int row0 = m0 + wr * 64;                 // token base of this wave's tile
    int b = row0 >> 11, nb = row0 & 2047;
    int h = colbase >> 6;
    int dl = lane;                           // this lane's d within the head
    unsigned short* gdst = vt + ((size_t)((b * 16 + h) * 64 + dl) * N_SEQ + nb);
    const unsigned short* srow = scr + dl * 64;
    int sw = (dl & 3) * 16;
#pragma unroll
    for (int j = 0; j < 8; ++j) {
      uint4 vv = *(const uint4*)(srow + ((j * 8) ^ sw));
      *(uint4*)(gdst + j * 8) = vv;
    }
  }
}

// ---------------------------------------------------------------------------
// Output projection: fp32 out = ao * Wo^T + bo. grid (32, 8).
// ---------------------------------------------------------------------------
__launch_bounds__(256)
__global__ void out_gemm(const unsigned short* __restrict__ ao,
                         const unsigned short* __restrict__ wob,
                         const float* __restrict__ bo,
                         float* __restrict__ out) {
  __shared__ unsigned short As[128 * 64];
  __shared__ unsigned short Bs[128 * 64];
  const int m0 = blockIdx.x * 128;
  const int e0 = blockIdx.y * 128;

  f32x4 acc[4][4];
#pragma unroll
  for (int mi = 0; mi < 4; ++mi)
#pragma unroll
    for (int ci = 0; ci < 4; ++ci) acc[mi][ci] = f32x4{0.f, 0.f, 0.f, 0.f};

  mainloop128(ao, wob, m0, e0, As, Bs, acc);

  const int lane = threadIdx.x & 63, wave = threadIdx.x >> 6;
  const int l16 = lane & 15, quad = lane >> 4;
  const int wr = wave >> 1, wc = wave & 1;
  float bcol[4];
#pragma unroll
  for (int ci = 0; ci < 4; ++ci) bcol[ci] = bo[e0 + wc * 64 + ci * 16 + l16];
#pragma unroll
  for (int mi = 0; mi < 4; ++mi)
#pragma unroll
    for (int ci = 0; ci < 4; ++ci) {
      int col = e0 + wc * 64 + ci * 16 + l16;
#pragma unroll
      for (int r = 0; r < 4; ++r) {
        int row = m0 + wr * 64 + mi * 16 + quad * 4 + r;
        out[(size_t)row * D_MODEL + col] = acc[mi][ci][r] + bcol[ci];
      }
    }
}

// ---------------------------------------------------------------------------
// Flash attention, no running max (LN'd q,k: |q.k/8| <= 8, |bias| ~ 5.5 ->
// exp can't overflow fp32). DOUBLE-BUFFERED K/Vt staging: prefetch for tile
// t+1 issued right after the barrier releasing tile t, so the end-of-tile
// barrier's vmcnt(0) drain overlaps with tile-t compute. Bias prefetched to
// registers before the S-MFMAs. LDS 40KB -> 4 blocks/CU.
// One block per (b, h, 64-row Q tile), 256 threads.
// ---------------------------------------------------------------------------
__launch_bounds__(256)
__global__ void attn_kernel(const unsigned short* __restrict__ Q,
                            const unsigned short* __restrict__ Kn,
                            const unsigned short* __restrict__ Vt,
                            const float* __restrict__ bias,
                            unsigned short* __restrict__ Out) {
  __shared__ unsigned short Qs[64 * 64];     // Q frags, then wave-private P scratch
  __shared__ unsigned short Ks[2][64 * 64];
  __shared__ unsigned short Vts[2][64 * 64];
  const int tid  = threadIdx.x;
  const int wave = tid >> 6, lane = tid & 63;
  const int quad = lane >> 4, l16 = lane & 15;
  const int bidx = blockIdx.x;
  const int qt = bidx & 31;
  const int h  = (bidx >> 5) & 15;
  const int b  = bidx >> 9;
  const int n0 = qt * 64;
  const size_t base  = (size_t)b * N_SEQ * D_MODEL + (size_t)h * 64;
  const unsigned short* vtb = Vt + (size_t)(b * 16 + h) * 64 * N_SEQ;

  auto stageKV = [&](int kt2, int bufi) {
#pragma unroll
    for (int r = 0; r < 2; ++r) {
      int c = r * 256 + tid;
      int row = c >> 3, col8 = c & 7;
      gload16(Kn + base + (size_t)(kt2 * 64 + row) * D_MODEL + col8 * 8,
              Ks[bufi] + (size_t)(r * 256 + wave * 64) * 8);
      gload16(vtb + (size_t)row * N_SEQ + kt2 * 64 + col8 * 8,
              Vts[bufi] + (size_t)(r * 256 + wave * 64) * 8);
    }
  };

  // ---- stage Q + K/V tile 0 ----
#pragma unroll
  for (int r = 0; r < 2; ++r) {
    int c = r * 256 + tid;
    int row = c >> 3, col8 = c & 7;
    gload16(Q + base + (size_t)(n0 + row) * D_MODEL + col8 * 8,
            Qs + (size_t)(r * 256 + wave * 64) * 8);
  }
  stageKV(0, 0);
  __syncthreads();
  bf16x8 aq[2];
  aq[0] = *(const bf16x8*)(Qs + (size_t)(wave * 16 + l16) * 64 + quad * 8);
  aq[1] = *(const bf16x8*)(Qs + (size_t)(wave * 16 + l16) * 64 + 32 + quad * 8);
  __builtin_amdgcn_wave_barrier();   // aq reads precede P writes (same rows)

  f32x4 o[4];
#pragma unroll
  for (int c = 0; c < 4; c++) o[c] = f32x4{0.f, 0.f, 0.f, 0.f};
  float lrow[4] = {0.f, 0.f, 0.f, 0.f};

  constexpr int NT = N_SEQ / 64;
  for (int kt = 0; kt < NT; ++kt) {
    const int cur = kt & 1;
    if (kt + 1 < NT) stageKV(kt + 1, cur ^ 1);   // in flight during compute

    // bias -> regs (issued before MFMA consumes LDS; latency overlapped)
    const float* bptr = bias + ((size_t)b * N_SEQ + n0 + wave * 16 + quad * 4) * N_SEQ + kt * 64;
    float breg[4][4];
#pragma unroll
    for (int c = 0; c < 4; c++)
#pragma unroll
      for (int r = 0; r < 4; r++)
        breg[c][r] = bptr[(size_t)r * N_SEQ + c * 16 + l16];

    // S = Q K^T (q pre-scaled by 0.125)
    f32x4 sf[4];
#pragma unroll
    for (int c = 0; c < 4; c++) {
      bf16x8 b0 = *(const bf16x8*)(Ks[cur] + (size_t)(c * 16 + l16) * 64 + quad * 8);
      bf16x8 b1 = *(const bf16x8*)(Ks[cur] + (size_t)(c * 16 + l16) * 64 + 32 + quad * 8);
      f32x4 z = f32x4{0.f, 0.f, 0.f, 0.f};
      z = __builtin_amdgcn_mfma_f32_16x16x32_bf16(aq[0], b0, z, 0, 0, 0);
      sf[c] = __builtin_amdgcn_mfma_f32_16x16x32_bf16(aq[1], b1, z, 0, 0, 0);
    }

    // p = exp(s + bias); accumulate l per lane; P -> swizzled LDS (bf16)
#pragma unroll
    for (int c = 0; c < 4; c++) {
#pragma unroll
      for (int r = 0; r < 4; r++) {
        float p = __expf(sf[c][r] + breg[c][r]);
        lrow[r] += p;
        Qs[(size_t)(wave * 16 + quad * 4 + r) * 64 + ((c ^ quad) * 16 + l16)] = f2bf(p);
      }
    }
    __builtin_amdgcn_wave_barrier();

    // O += P V  (pa from swizzled P rows; bv = Vt rows, contiguous b128)
#pragma unroll
    for (int ks = 0; ks < 2; ks++) {
      int colsw = (ks * 32 + quad * 8) ^ ((l16 >> 2) * 16);
      bf16x8 pa = *(const bf16x8*)(Qs + (size_t)(wave * 16 + l16) * 64 + colsw);
#pragma unroll
      for (int c = 0; c < 4; c++) {
        bf16x8 bv = *(const bf16x8*)(Vts[cur] + (size_t)(c * 16 + l16) * 64 + ks * 32 + quad * 8);
        o[c] = __builtin_amdgcn_mfma_f32_16x16x32_bf16(pa, bv, o[c], 0, 0, 0);
      }
    }
    __syncthreads();   // drains prefetch (t+1) + protects buf reuse
  }

  // final row-sum reduction across the 16 lanes sharing each row, then store
#pragma unroll
  for (int r = 0; r < 4; r++) {
    float l = lrow[r];
    l += __shfl_xor(l, 1); l += __shfl_xor(l, 2);
    l += __shfl_xor(l, 4); l += __shfl_xor(l, 8);
    float inv = 1.0f / l;
    size_t row = (size_t)b * N_SEQ + n0 + wave * 16 + quad * 4 + r;
#pragma unroll
    for (int c = 0; c < 4; c++)
      Out[row * D_MODEL + h * 64 + c * 16 + l16] = f2bf(o[c][r] * inv);
  }
}

extern "C" void kernel_launch(void* const* d_in, const int* in_sizes, int n_in,
                              void* d_out, int out_size, void* d_ws, size_t ws_size,
                              hipStream_t stream) {
  const float* x    = (const float*)d_in[0];
  const float* bias = (const float*)d_in[1];
  const float* Wq = (const float*)d_in[2];  const float* bq = (const float*)d_in[3];
  const float* Wk = (const float*)d_in[4];  const float* bk = (const float*)d_in[5];
  const float* Wv = (const float*)d_in[6];  const float* bv = (const float*)d_in[7];
  const float* Wo = (const float*)d_in[8];  const float* bo = (const float*)d_in[9];
  const float* qg = (const float*)d_in[10]; const float* qb = (const float*)d_in[11];
  const float* kg = (const float*)d_in[12]; const float* kb = (const float*)d_in[13];
  float* out = (float*)d_out;

  unsigned short* wsb = (unsigned short*)d_ws;
  unsigned short* xb  = wsb;                 // 4M (reused as ao after qkv_gemm)
  unsigned short* wqb = wsb + XEL;           // 4 x 1M weights
  unsigned short* wob = wsb + XEL + 3 * WEL;
  unsigned short* qn  = wsb + XEL + 4 * WEL; // 4M
  unsigned short* kn  = qn + XEL;            // 4M
  unsigned short* vt  = qn + 2 * XEL;        // 4M, transposed per-(b,h)
  unsigned short* ao  = xb;                  // alias: xb dead after qkv_gemm

  dim3 blk(256, 1, 1);

  cvt_kernel<<<dim3((unsigned)((XEL + 4 * WEL) / (256 * 8)), 1, 1), blk, 0, stream>>>(
      x, Wq, Wk, Wv, Wo, wsb);

  qkv_gemm<<<dim3(M_ROWS / 128, 24, 1), blk, 0, stream>>>(
      xb, wqb, bq, bk, bv, qg, qb, kg, kb, qn, vt);

  attn_kernel<<<dim3(N_B * 16 * (N_SEQ / 64), 1, 1), blk, 0, stream>>>(qn, kn, vt, bias, ao);

  out_gemm<<<dim3(M_ROWS / 128, D_MODEL / 128, 1), blk, 0, stream>>>(ao, wob, bo, out);
}

// Round 5
// 276.434 us; speedup vs baseline: 1.0244x; 1.0244x over previous
//
#include <hip/hip_runtime.h>
#include <hip/hip_bf16.h>

#define D_MODEL 1024
#define N_SEQ   2048
#define N_B     2
#define M_ROWS  (N_B * N_SEQ)   // 4096

typedef __attribute__((ext_vector_type(8))) short bf16x8;
typedef __attribute__((ext_vector_type(4))) float f32x4;

typedef const __attribute__((address_space(1))) unsigned int gu32_t;
typedef __attribute__((address_space(3))) unsigned int lu32_t;

__device__ __forceinline__ void gload16(const void* g, void* l) {
  // async global->LDS, 16B per lane; LDS dest = wave-uniform base + lane*16
  __builtin_amdgcn_global_load_lds((gu32_t*)g, (lu32_t*)l, 16, 0, 0);
}

__device__ inline unsigned short f2bf(float f) {
  union { float f; unsigned int u; } v; v.f = f;
  unsigned int r = (v.u + 0x7FFFu + ((v.u >> 16) & 1u)) >> 16;
  return (unsigned short)r;
}

// Bank-conflict swizzle for 64-col (128B-row) LDS tiles:
// logical 16B-chunk k of row r lives at physical chunk k ^ (r & 7).
// Fragment reads (8 contiguous ushorts, chunk-aligned) become 2-way max.
__device__ __forceinline__ int lds_off(int row, int col /*ushort idx*/) {
  return row * 64 + (((col >> 3) ^ (row & 7)) << 3) + (col & 7);
}

// Stage a ROWS x 64-ushort tile global->LDS with the swizzle applied on the
// global-source side (LDS destination must stay linear for global_load_lds).
template<int ROWS>
__device__ __forceinline__ void stage_tile(const unsigned short* gbase, size_t gstride,
                                           unsigned short* lds, int tid) {
  const int wave = tid >> 6;
#pragma unroll
  for (int rnd = 0; rnd < ROWS / 32; ++rnd) {
    int c = rnd * 256 + tid;
    int row = c >> 3, pc = c & 7;
    int gcol = ((pc ^ (row & 7)) << 3);
    gload16(gbase + (size_t)row * gstride + gcol,
            lds + (size_t)(rnd * 256 + wave * 64) * 8);
  }
}

constexpr size_t XEL = (size_t)M_ROWS * D_MODEL;     // 4194304
constexpr size_t WEL = (size_t)D_MODEL * D_MODEL;    // 1048576

// ---------------------------------------------------------------------------
// fp32 -> bf16 convert for [x (4M) | Wq | Wk | Wv | Wo (1M each)] -> ws
// ---------------------------------------------------------------------------
__launch_bounds__(256)
__global__ void cvt_kernel(const float* __restrict__ x,
                           const float* __restrict__ wq, const float* __restrict__ wk,
                           const float* __restrict__ wv, const float* __restrict__ wo,
                           unsigned short* __restrict__ dst) {
  size_t i = ((size_t)blockIdx.x * 256 + threadIdx.x) * 8;
  if (i >= XEL + 4 * WEL) return;
  const float* s; size_t off = i;
  if (off < XEL)                { s = x; }
  else if (off < XEL + WEL)     { s = wq; off -= XEL; }
  else if (off < XEL + 2*WEL)   { s = wk; off -= XEL + WEL; }
  else if (off < XEL + 3*WEL)   { s = wv; off -= XEL + 2*WEL; }
  else                          { s = wo; off -= XEL + 3*WEL; }
  float4 f0 = *(const float4*)(s + off);
  float4 f1 = *(const float4*)(s + off + 4);
  unsigned short t[8] = { f2bf(f0.x), f2bf(f0.y), f2bf(f0.z), f2bf(f0.w),
                          f2bf(f1.x), f2bf(f1.y), f2bf(f1.z), f2bf(f1.w) };
  *(uint4*)(dst + i) = *(const uint4*)t;
}

// ---------------------------------------------------------------------------
// m97-style 128x128 bf16 mainloop, swizzled LDS: C = A * Bw^T
// 4 waves in 2x2; wave (wr,wc) owns rows wr*64.., cols wc*64..; acc[mi][ci].
// ---------------------------------------------------------------------------
__device__ __forceinline__ void mainloop128(const unsigned short* __restrict__ A,
                                            const unsigned short* __restrict__ Bw,
                                            int m0, int e0,
                                            unsigned short* As, unsigned short* Bs,
                                            f32x4 (&acc)[4][4]) {
  const int tid  = threadIdx.x;
  const int wave = tid >> 6, lane = tid & 63;
  const int l16 = lane & 15, quad = lane >> 4;
  const int wr = wave >> 1, wc = wave & 1;

  for (int kt = 0; kt < D_MODEL / 64; ++kt) {
    const int k0 = kt * 64;
    stage_tile<128>(A + (size_t)m0 * D_MODEL + k0, D_MODEL, As, tid);
    stage_tile<128>(Bw + (size_t)e0 * D_MODEL + k0, D_MODEL, Bs, tid);
    __syncthreads();
#pragma unroll
    for (int ks = 0; ks < 2; ++ks) {
      bf16x8 af[4], bfr[4];
#pragma unroll
      for (int mi = 0; mi < 4; ++mi)
        af[mi] = *(const bf16x8*)(As + lds_off(wr * 64 + mi * 16 + l16, ks * 32 + quad * 8));
#pragma unroll
      for (int ci = 0; ci < 4; ++ci)
        bfr[ci] = *(const bf16x8*)(Bs + lds_off(wc * 64 + ci * 16 + l16, ks * 32 + quad * 8));
#pragma unroll
      for (int mi = 0; mi < 4; ++mi)
#pragma unroll
        for (int ci = 0; ci < 4; ++ci)
          acc[mi][ci] = __builtin_amdgcn_mfma_f32_16x16x32_bf16(af[mi], bfr[ci], acc[mi][ci], 0, 0, 0);
    }
    __syncthreads();
  }
}

// ---------------------------------------------------------------------------
// Fused Q/K/V projection. grid (32, 24): by -> {mat = by>>3, e0 = (by&7)*128}.
// mat 0 (q): LN epilogue with 0.125 softmax scale folded in.
// mat 1 (k): LN epilogue.
// mat 2 (v): V stored TRANSPOSED per (b,h) via LDS repack, coalesced rows.
// ---------------------------------------------------------------------------
__launch_bounds__(256)
__global__ void qkv_gemm(const unsigned short* __restrict__ xb,
                         const unsigned short* __restrict__ wb,   // wq|wk|wv bf16
                         const float* __restrict__ bq, const float* __restrict__ bk,
                         const float* __restrict__ bv,
                         const float* __restrict__ qg, const float* __restrict__ qbeta,
                         const float* __restrict__ kg, const float* __restrict__ kbeta,
                         unsigned short* __restrict__ qkout,      // qn | kn
                         unsigned short* __restrict__ vt) {
  __shared__ unsigned short As[128 * 64];
  __shared__ unsigned short Bs[128 * 64];
  const int m0  = blockIdx.x * 128;
  const int by  = blockIdx.y;
  const int mat = by >> 3;
  const int e0  = (by & 7) * 128;
  const unsigned short* Bw = wb + (size_t)mat * WEL;

  f32x4 acc[4][4];
#pragma unroll
  for (int mi = 0; mi < 4; ++mi)
#pragma unroll
    for (int ci = 0; ci < 4; ++ci) acc[mi][ci] = f32x4{0.f, 0.f, 0.f, 0.f};

  mainloop128(xb, Bw, m0, e0, As, Bs, acc);

  const int lane = threadIdx.x & 63, wave = threadIdx.x >> 6;
  const int l16 = lane & 15, quad = lane >> 4;
  const int wr = wave >> 1, wc = wave & 1;
  const int colbase = e0 + wc * 64;          // multiple of 64 -> one head per wave

  const float* bias = (mat == 0) ? bq : ((mat == 1) ? bk : bv);
  float bcol[4];
#pragma unroll
  for (int ci = 0; ci < 4; ++ci) bcol[ci] = bias[colbase + ci * 16 + l16];
#pragma unroll
  for (int mi = 0; mi < 4; ++mi)
#pragma unroll
    for (int ci = 0; ci < 4; ++ci)
#pragma unroll
      for (int r = 0; r < 4; ++r) acc[mi][ci][r] += bcol[ci];

  if (mat < 2) {
    const float* gamma = (mat == 0) ? qg : kg;
    const float* beta  = (mat == 0) ? qbeta : kbeta;
    const float sc = (mat == 0) ? 0.125f : 1.0f;   // fold softmax scale into q
    float g4[4], bt4[4];
#pragma unroll
    for (int ci = 0; ci < 4; ++ci) {
      g4[ci] = gamma[ci * 16 + l16] * sc;
      bt4[ci] = beta[ci * 16 + l16] * sc;
    }
#pragma unroll
    for (int mi = 0; mi < 4; ++mi)
#pragma unroll
      for (int r = 0; r < 4; ++r) {
        float s = acc[mi][0][r] + acc[mi][1][r] + acc[mi][2][r] + acc[mi][3][r];
        s += __shfl_xor(s, 1); s += __shfl_xor(s, 2);
        s += __shfl_xor(s, 4); s += __shfl_xor(s, 8);
        float mean = s * (1.f / 64.f);
        float d0 = acc[mi][0][r] - mean, d1 = acc[mi][1][r] - mean;
        float d2 = acc[mi][2][r] - mean, d3 = acc[mi][3][r] - mean;
        float q = d0 * d0 + d1 * d1 + d2 * d2 + d3 * d3;
        q += __shfl_xor(q, 1); q += __shfl_xor(q, 2);
        q += __shfl_xor(q, 4); q += __shfl_xor(q, 8);
        float rs = rsqrtf(q * (1.f / 64.f) + 1e-6f);
        acc[mi][0][r] = d0 * rs * g4[0] + bt4[0];
        acc[mi][1][r] = d1 * rs * g4[1] + bt4[1];
        acc[mi][2][r] = d2 * rs * g4[2] + bt4[2];
        acc[mi][3][r] = d3 * rs * g4[3] + bt4[3];
      }
    unsigned short* out = qkout + (size_t)mat * XEL;
#pragma unroll
    for (int mi = 0; mi < 4; ++mi)
#pragma unroll
      for (int ci = 0; ci < 4; ++ci) {
        int col = colbase + ci * 16 + l16;
#pragma unroll
        for (int r = 0; r < 4; ++r) {
          int row = m0 + wr * 64 + mi * 16 + quad * 4 + r;
          out[(size_t)row * D_MODEL + col] = f2bf(acc[mi][ci][r]);
        }
      }
  } else {
    // V transpose via wave-private LDS scratch (col-swizzled), then each lane
    // stores one full d-row (128B) as 8x dwordx4 -> coalesced.
    unsigned short* scr = ((wave < 2) ? As : Bs) + (size_t)(wave & 1) * 4096;
#pragma unroll
    for (int ci = 0; ci < 4; ++ci) {
      int dl = ci * 16 + l16;
      int sw = (dl & 3) * 16;
#pragma unroll
      for (int mi = 0; mi < 4; ++mi)
#pragma unroll
        for (int r = 0; r < 4; ++r) {
          int nl = mi * 16 + quad * 4 + r;
          scr[dl * 64 + (nl ^ sw)] = f2bf(acc[mi][ci][r]);
        }
    }
    __builtin_amdgcn_wave_barrier();
    int row0 = m0 + wr * 64;                 // token base of this wave's tile
    int b = row0 >> 11, nb = row0 & 2047;
    int h = colbase >> 6;
    int dl = lane;                           // this lane's d within the head
    unsigned short* gdst = vt + ((size_t)((b * 16 + h) * 64 + dl) * N_SEQ + nb);
    const unsigned short* srow = scr + dl * 64;
    int sw = (dl & 3) * 16;
#pragma unroll
    for (int j = 0; j < 8; ++j) {
      uint4 vv = *(const uint4*)(srow + ((j * 8) ^ sw));
      *(uint4*)(gdst + j * 8) = vv;
    }
  }
}

// ---------------------------------------------------------------------------
// Output projection: fp32 out = ao * Wo^T + bo. grid (32, 8).
// ---------------------------------------------------------------------------
__launch_bounds__(256)
__global__ void out_gemm(const unsigned short* __restrict__ ao,
                         const unsigned short* __restrict__ wob,
                         const float* __restrict__ bo,
                         float* __restrict__ out) {
  __shared__ unsigned short As[128 * 64];
  __shared__ unsigned short Bs[128 * 64];
  const int m0 = blockIdx.x * 128;
  const int e0 = blockIdx.y * 128;

  f32x4 acc[4][4];
#pragma unroll
  for (int mi = 0; mi < 4; ++mi)
#pragma unroll
    for (int ci = 0; ci < 4; ++ci) acc[mi][ci] = f32x4{0.f, 0.f, 0.f, 0.f};

  mainloop128(ao, wob, m0, e0, As, Bs, acc);

  const int lane = threadIdx.x & 63, wave = threadIdx.x >> 6;
  const int l16 = lane & 15, quad = lane >> 4;
  const int wr = wave >> 1, wc = wave & 1;
  float bcol[4];
#pragma unroll
  for (int ci = 0; ci < 4; ++ci) bcol[ci] = bo[e0 + wc * 64 + ci * 16 + l16];
#pragma unroll
  for (int mi = 0; mi < 4; ++mi)
#pragma unroll
    for (int ci = 0; ci < 4; ++ci) {
      int col = e0 + wc * 64 + ci * 16 + l16;
#pragma unroll
      for (int r = 0; r < 4; ++r) {
        int row = m0 + wr * 64 + mi * 16 + quad * 4 + r;
        out[(size_t)row * D_MODEL + col] = acc[mi][ci][r] + bcol[ci];
      }
    }
}

// ---------------------------------------------------------------------------
// Flash attention, no running max (LN'd q,k + |bias| bound -> exp safe).
// 128 Q-rows per block (32 per wave): K/V fragments feed 2x the MFMAs ->
// 20 b128 LDS reads per 32 MFMAs per wave-tile. All LDS tiles XOR-swizzled
// (2-way max conflicts). Double-buffered K/Vt staging. Grid 512 = 2/CU.
// ---------------------------------------------------------------------------
__launch_bounds__(256)
__global__ void attn_kernel(const unsigned short* __restrict__ Q,
                            const unsigned short* __restrict__ Kn,
                            const unsigned short* __restrict__ Vt,
                            const float* __restrict__ bias,
                            unsigned short* __restrict__ Out) {
  __shared__ unsigned short Qs[128 * 64];    // Q frags, then wave-private P scratch
  __shared__ unsigned short Ks[2][64 * 64];
  __shared__ unsigned short Vts[2][64 * 64];
  const int tid  = threadIdx.x;
  const int wave = tid >> 6, lane = tid & 63;
  const int quad = lane >> 4, l16 = lane & 15;
  const int bidx = blockIdx.x;
  const int qt = bidx & 15;                  // 16 q-tiles of 128
  const int h  = (bidx >> 4) & 15;
  const int b  = bidx >> 8;
  const int q0 = qt * 128;
  const size_t base  = (size_t)b * N_SEQ * D_MODEL + (size_t)h * 64;
  const unsigned short* vtb = Vt + (size_t)(b * 16 + h) * 64 * N_SEQ;

  // ---- stage Q (128 rows) + K/V tile 0 ----
  stage_tile<128>(Q + base + (size_t)q0 * D_MODEL, D_MODEL, Qs, tid);
  stage_tile<64>(Kn + base, D_MODEL, Ks[0], tid);
  stage_tile<64>(vtb, N_SEQ, Vts[0], tid);
  __syncthreads();
  bf16x8 aq[2][2];                           // [mi][ks]
#pragma unroll
  for (int mi = 0; mi < 2; ++mi)
#pragma unroll
    for (int ks = 0; ks < 2; ++ks)
      aq[mi][ks] = *(const bf16x8*)(Qs + lds_off(wave * 32 + mi * 16 + l16, ks * 32 + quad * 8));
  __builtin_amdgcn_wave_barrier();           // aq reads precede P writes (same rows)

  f32x4 o[2][4];
#pragma unroll
  for (int mi = 0; mi < 2; ++mi)
#pragma unroll
    for (int c = 0; c < 4; ++c) o[mi][c] = f32x4{0.f, 0.f, 0.f, 0.f};
  float lrow[2][4] = {{0.f,0.f,0.f,0.f},{0.f,0.f,0.f,0.f}};

  constexpr int NT = N_SEQ / 64;
  for (int kt = 0; kt < NT; ++kt) {
    const int cur = kt & 1;
    if (kt + 1 < NT) {                       // prefetch overlaps this tile
      stage_tile<64>(Kn + base + (size_t)(kt + 1) * 64 * D_MODEL, D_MODEL, Ks[cur ^ 1], tid);
      stage_tile<64>(vtb + (kt + 1) * 64, N_SEQ, Vts[cur ^ 1], tid);
    }

    // bias -> regs (VMEM pipe; latency overlaps the S MFMAs)
    const float* bptr = bias + ((size_t)b * N_SEQ + q0 + wave * 32 + quad * 4) * N_SEQ + kt * 64;
    float breg[2][4][4];
#pragma unroll
    for (int mi = 0; mi < 2; ++mi)
#pragma unroll
      for (int c = 0; c < 4; ++c)
#pragma unroll
        for (int r = 0; r < 4; ++r)
          breg[mi][c][r] = bptr[(size_t)(mi * 16 + r) * N_SEQ + c * 16 + l16];

    // S = Q K^T (q pre-scaled by 0.125); K frags reused across both mi
    f32x4 sf[2][4];
#pragma unroll
    for (int c = 0; c < 4; ++c) {
      bf16x8 b0 = *(const bf16x8*)(Ks[cur] + lds_off(c * 16 + l16, quad * 8));
      bf16x8 b1 = *(const bf16x8*)(Ks[cur] + lds_off(c * 16 + l16, 32 + quad * 8));
#pragma unroll
      for (int mi = 0; mi < 2; ++mi) {
        f32x4 z = f32x4{0.f, 0.f, 0.f, 0.f};
        z = __builtin_amdgcn_mfma_f32_16x16x32_bf16(aq[mi][0], b0, z, 0, 0, 0);
        sf[mi][c] = __builtin_amdgcn_mfma_f32_16x16x32_bf16(aq[mi][1], b1, z, 0, 0, 0);
      }
    }

    // p = exp(s + bias); accumulate l per lane; P -> swizzled LDS (bf16)
    __builtin_amdgcn_wave_barrier();         // prev pa reads precede P rewrite
#pragma unroll
    for (int mi = 0; mi < 2; ++mi)
#pragma unroll
      for (int c = 0; c < 4; ++c)
#pragma unroll
        for (int r = 0; r < 4; ++r) {
          float p = __expf(sf[mi][c][r] + breg[mi][c][r]);
          lrow[mi][r] += p;
          Qs[lds_off(wave * 32 + mi * 16 + quad * 4 + r, c * 16 + l16)] = f2bf(p);
        }
    __builtin_amdgcn_wave_barrier();

    // O += P V  (bv frags reused across both mi)
#pragma unroll
    for (int ks = 0; ks < 2; ++ks) {
      bf16x8 bv[4];
#pragma unroll
      for (int c = 0; c < 4; ++c)
        bv[c] = *(const bf16x8*)(Vts[cur] + lds_off(c * 16 + l16, ks * 32 + quad * 8));
#pragma unroll
      for (int mi = 0; mi < 2; ++mi) {
        bf16x8 pa = *(const bf16x8*)(Qs + lds_off(wave * 32 + mi * 16 + l16, ks * 32 + quad * 8));
#pragma unroll
        for (int c = 0; c < 4; ++c)
          o[mi][c] = __builtin_amdgcn_mfma_f32_16x16x32_bf16(pa, bv[c], o[mi][c], 0, 0, 0);
      }
    }
    __syncthreads();   // all waves done with buf cur; prefetch cur^1 drained
  }

  // final row-sum reduction across the 16 lanes sharing each row, then store
#pragma unroll
  for (int mi = 0; mi < 2; ++mi)
#pragma unroll
    for (int r = 0; r < 4; ++r) {
      float l = lrow[mi][r];
      l += __shfl_xor(l, 1); l += __shfl_xor(l, 2);
      l += __shfl_xor(l, 4); l += __shfl_xor(l, 8);
      float inv = 1.0f / l;
      size_t row = (size_t)b * N_SEQ + q0 + wave * 32 + mi * 16 + quad * 4 + r;
#pragma unroll
      for (int c = 0; c < 4; ++c)
        Out[row * D_MODEL + h * 64 + c * 16 + l16] = f2bf(o[mi][c][r] * inv);
    }
}

extern "C" void kernel_launch(void* const* d_in, const int* in_sizes, int n_in,
                              void* d_out, int out_size, void* d_ws, size_t ws_size,
                              hipStream_t stream) {
  const float* x    = (const float*)d_in[0];
  const float* bias = (const float*)d_in[1];
  const float* Wq = (const float*)d_in[2];  const float* bq = (const float*)d_in[3];
  const float* Wk = (const float*)d_in[4];  const float* bk = (const float*)d_in[5];
  const float* Wv = (const float*)d_in[6];  const float* bv = (const float*)d_in[7];
  const float* Wo = (const float*)d_in[8];  const float* bo = (const float*)d_in[9];
  const float* qg = (const float*)d_in[10]; const float* qb = (const float*)d_in[11];
  const float* kg = (const float*)d_in[12]; const float* kb = (const float*)d_in[13];
  float* out = (float*)d_out;

  unsigned short* wsb = (unsigned short*)d_ws;
  unsigned short* xb  = wsb;                 // 4M (reused as ao after qkv_gemm)
  unsigned short* wqb = wsb + XEL;           // 4 x 1M weights
  unsigned short* wob = wsb + XEL + 3 * WEL;
  unsigned short* qn  = wsb + XEL + 4 * WEL; // 4M
  unsigned short* kn  = qn + XEL;            // 4M
  unsigned short* vt  = qn + 2 * XEL;        // 4M, transposed per-(b,h)
  unsigned short* ao  = xb;                  // alias: xb dead after qkv_gemm

  dim3 blk(256, 1, 1);

  cvt_kernel<<<dim3((unsigned)((XEL + 4 * WEL) / (256 * 8)), 1, 1), blk, 0, stream>>>(
      x, Wq, Wk, Wv, Wo, wsb);

  qkv_gemm<<<dim3(M_ROWS / 128, 24, 1), blk, 0, stream>>>(
      xb, wqb, bq, bk, bv, qg, qb, kg, kb, qn, vt);

  attn_kernel<<<dim3(N_B * 16 * (N_SEQ / 128), 1, 1), blk, 0, stream>>>(qn, kn, vt, bias, ao);

  out_gemm<<<dim3(M_ROWS / 128, D_MODEL / 128, 1), blk, 0, stream>>>(ao, wob, bo, out);
}